// Round 6
// baseline (47.332 us; speedup 1.0000x reference)
//
#include <hip/hip_runtime.h>
#include <float.h>

#define NS 50
#define NP 64              // padded to power of two for bitonic network
#define B_DIM 8192
#define D_DIM 64
#define BD (B_DIM * D_DIM)
#define BLOCK 256
#define EPT 2              // elements per thread
#define GRID (BD / (BLOCK * EPT))   // 1024

// Compute one element's pre-scaled-by-nothing energy from its raw noise
// values in s[0..NS-1] (s is clobbered). All indices compile-time.
__device__ __forceinline__ float elem_energy(float* s, float m, float sd, float t) {
    float f0 = 0.0f, f1 = 0.0f;
    #pragma unroll
    for (int k = 0; k < NS; ++k) {
        s[k] = fmaf(s[k], sd, m);
        float d = fabsf(s[k] - t);
        if (k & 1) f1 += d;
        else       f0 += d;
    }
    #pragma unroll
    for (int k = NS; k < NP; ++k) s[k] = FLT_MAX;

    // Bitonic sort network, 64 elems, fully unrolled, compile-time dirs.
    #pragma unroll
    for (int k = 2; k <= NP; k <<= 1) {
        #pragma unroll
        for (int j = k >> 1; j > 0; j >>= 1) {
            #pragma unroll
            for (int i = 0; i < NP; ++i) {
                const int l = i ^ j;
                if (l > i) {
                    const bool up = ((i & k) == 0);
                    float x = s[i], y = s[l];
                    float lo = fminf(x, y);
                    float hi = fmaxf(x, y);
                    s[i] = up ? lo : hi;
                    s[l] = up ? hi : lo;
                }
            }
        }
    }

    // sum_{i<j}|s_i-s_j| == sum_k (2k-(n-1)) * sorted_k
    float p0 = 0.0f, p1 = 0.0f;
    #pragma unroll
    for (int k = 0; k < NS; ++k) {
        const float c = (float)(2 * k - (NS - 1));
        if (k & 1) p1 = fmaf(c, s[k], p1);
        else       p0 = fmaf(c, s[k], p0);
    }
    return (f0 + f1) * (1.0f / NS) - (p0 + p1) * (1.0f / 2450.0f);
}

__device__ __forceinline__ float block_reduce(float e, int tid) {
    #pragma unroll
    for (int off = 32; off > 0; off >>= 1)
        e += __shfl_down(e, off, 64);
    __shared__ float wsum[BLOCK / 64];
    const int lane = tid & 63;
    const int wid  = tid >> 6;
    if (lane == 0) wsum[wid] = e;
    __syncthreads();
    float bs = 0.0f;
    if (tid == 0) {
        #pragma unroll
        for (int w = 0; w < BLOCK / 64; ++w) bs += wsum[w];
    }
    return bs;
}

// Stage 1: two elements per thread. Issue A's 50 loads, then B's 50 loads
// (all in flight), compute A (counted vmcnt leaves B outstanding -> B's
// latency hides under A's bitonic), compute B. Plain store of block sum.
__global__ __launch_bounds__(BLOCK, 3) void energy_partial_kernel(
    const float* __restrict__ mean, const float* __restrict__ variance,
    const float* __restrict__ noise, const float* __restrict__ target,
    float* __restrict__ partial) {

    const int tid  = threadIdx.x;
    const int idx0 = blockIdx.x * BLOCK + tid;       // [0, BD/2)
    const int idx1 = idx0 + BD / 2;

    // ---- Issue phase: element A loads first, element B loads second.
    float a[NP], b[NP];
    const float* n0 = noise + idx0;
    const float* n1 = noise + idx1;
    #pragma unroll
    for (int k = 0; k < NS; ++k) a[k] = n0[(size_t)k * BD];
    #pragma unroll
    for (int k = 0; k < NS; ++k) b[k] = n1[(size_t)k * BD];

    const float m0 = mean[idx0],  m1 = mean[idx1];
    const float v0 = variance[idx0], v1 = variance[idx1];
    const float t0 = target[idx0], t1 = target[idx1];
    const float sd0 = sqrtf(v0 + 1e-6f);
    const float sd1 = sqrtf(v1 + 1e-6f);

    // ---- Compute A (B's loads still in flight), then compute B.
    float e = elem_energy(a, m0, sd0, t0);
    e += elem_energy(b, m1, sd1, t1);
    e *= (1.0f / (float)BD);

    float bs = block_reduce(e, tid);
    if (tid == 0) partial[blockIdx.x] = bs;
}

// Stage 2: one block sums the partials, writes the scalar output.
__global__ __launch_bounds__(BLOCK) void reduce_partial_kernel(
    const float* __restrict__ partial, float* __restrict__ out) {
    float e = 0.0f;
    #pragma unroll
    for (int i = 0; i < GRID / BLOCK; ++i)
        e += partial[i * BLOCK + threadIdx.x];
    float bs = block_reduce(e, threadIdx.x);
    if (threadIdx.x == 0) out[0] = bs;   // overwrites poison
}

// Fallback (ws too small): single-kernel atomic path, same pipeline.
__global__ __launch_bounds__(BLOCK, 3) void energy_atomic_kernel(
    const float* __restrict__ mean, const float* __restrict__ variance,
    const float* __restrict__ noise, const float* __restrict__ target,
    float* __restrict__ out) {
    const int tid  = threadIdx.x;
    const int idx0 = blockIdx.x * BLOCK + tid;
    const int idx1 = idx0 + BD / 2;
    float a[NP], b[NP];
    const float* n0 = noise + idx0;
    const float* n1 = noise + idx1;
    #pragma unroll
    for (int k = 0; k < NS; ++k) a[k] = n0[(size_t)k * BD];
    #pragma unroll
    for (int k = 0; k < NS; ++k) b[k] = n1[(size_t)k * BD];
    const float m0 = mean[idx0],  m1 = mean[idx1];
    const float v0 = variance[idx0], v1 = variance[idx1];
    const float t0 = target[idx0], t1 = target[idx1];
    float e = elem_energy(a, m0, sqrtf(v0 + 1e-6f), t0)
            + elem_energy(b, m1, sqrtf(v1 + 1e-6f), t1);
    e *= (1.0f / (float)BD);
    float bs = block_reduce(e, tid);
    if (tid == 0) atomicAdd(out, bs);
}

extern "C" void kernel_launch(void* const* d_in, const int* in_sizes, int n_in,
                              void* d_out, int out_size, void* d_ws, size_t ws_size,
                              hipStream_t stream) {
    const float* mean     = (const float*)d_in[0];
    const float* variance = (const float*)d_in[1];
    const float* noise    = (const float*)d_in[2];
    const float* target   = (const float*)d_in[3];
    float* out = (float*)d_out;

    if (ws_size >= (size_t)GRID * sizeof(float)) {
        float* partial = (float*)d_ws;
        energy_partial_kernel<<<GRID, BLOCK, 0, stream>>>(mean, variance, noise,
                                                          target, partial);
        reduce_partial_kernel<<<1, BLOCK, 0, stream>>>(partial, out);
    } else {
        hipMemsetAsync(out, 0, sizeof(float), stream);
        energy_atomic_kernel<<<GRID, BLOCK, 0, stream>>>(mean, variance, noise,
                                                         target, out);
    }
}

// Round 7
// 35.272 us; speedup vs baseline: 1.3419x; 1.3419x over previous
//
#include <hip/hip_runtime.h>
#include <float.h>

#define NS 50
#define NP 64              // padded to power of two for bitonic network
#define B_DIM 8192
#define D_DIM 64
#define BD (B_DIM * D_DIM)
#define BLOCK 256
#define GRID (BD / BLOCK)  // 2048

// ---- Core per-element pipeline (verified R2-R6): returns pre-scaled energy.
__device__ __forceinline__ float energy_elem(const float* __restrict__ mean,
                                             const float* __restrict__ variance,
                                             const float* __restrict__ noise,
                                             const float* __restrict__ target,
                                             int idx) {
    const float m = mean[idx];
    const float v = variance[idx];
    const float t = target[idx];
    const float sd = sqrtf(v + 1e-6f);

    float s[NP];
    const float* np_ = noise + idx;
    #pragma unroll
    for (int k = 0; k < NS; ++k) s[k] = np_[(size_t)k * BD];

    float f0 = 0.0f, f1 = 0.0f;
    #pragma unroll
    for (int k = 0; k < NS; ++k) {
        s[k] = fmaf(s[k], sd, m);
        float d = fabsf(s[k] - t);
        if (k & 1) f1 += d;
        else       f0 += d;
    }
    #pragma unroll
    for (int k = NS; k < NP; ++k) s[k] = FLT_MAX;

    // Bitonic sort network, 64 elems, fully unrolled, compile-time dirs.
    #pragma unroll
    for (int k = 2; k <= NP; k <<= 1) {
        #pragma unroll
        for (int j = k >> 1; j > 0; j >>= 1) {
            #pragma unroll
            for (int i = 0; i < NP; ++i) {
                const int l = i ^ j;
                if (l > i) {
                    const bool up = ((i & k) == 0);
                    float a = s[i], b = s[l];
                    float lo = fminf(a, b);
                    float hi = fmaxf(a, b);
                    s[i] = up ? lo : hi;
                    s[l] = up ? hi : lo;
                }
            }
        }
    }

    // sum_{i<j}|s_i-s_j| == sum_k (2k-(n-1)) * sorted_k
    float p0 = 0.0f, p1 = 0.0f;
    #pragma unroll
    for (int k = 0; k < NS; ++k) {
        const float c = (float)(2 * k - (NS - 1));
        if (k & 1) p1 = fmaf(c, s[k], p1);
        else       p0 = fmaf(c, s[k], p0);
    }

    float e = (f0 + f1) * (1.0f / NS) - (p0 + p1) * (1.0f / 2450.0f);
    return e * (1.0f / (float)BD);   // pre-scale for global mean
}

__device__ __forceinline__ float block_reduce(float e, int tid) {
    #pragma unroll
    for (int off = 32; off > 0; off >>= 1)
        e += __shfl_down(e, off, 64);
    __shared__ float wsum[BLOCK / 64];
    const int lane = tid & 63;
    const int wid  = tid >> 6;
    if (lane == 0) wsum[wid] = e;
    __syncthreads();
    float bs = 0.0f;
    if (tid == 0) {
        #pragma unroll
        for (int w = 0; w < BLOCK / 64; ++w) bs += wsum[w];
    }
    return bs;
}

// Stage 1: per-block partial sum -> plain store (no atomics).
// Bijective XCD swizzle (2048 % 8 == 0): hardware block B (XCD = B%8)
// processes work chunk (B%8)*256 + B/8, so each XCD covers a CONTIGUOUS
// 256KB window per noise row -> all L2 channels active, L2/L3 locality.
__global__ __launch_bounds__(BLOCK) void energy_partial_kernel(
    const float* __restrict__ mean, const float* __restrict__ variance,
    const float* __restrict__ noise, const float* __restrict__ target,
    float* __restrict__ partial) {
    const int wg  = (blockIdx.x & 7) * (GRID / 8) + (blockIdx.x >> 3);
    const int idx = wg * BLOCK + threadIdx.x;
    float e = energy_elem(mean, variance, noise, target, idx);
    float bs = block_reduce(e, threadIdx.x);
    if (threadIdx.x == 0) partial[blockIdx.x] = bs;
}

// Stage 2: one block sums the 2048 partials, writes the scalar output.
__global__ __launch_bounds__(BLOCK) void reduce_partial_kernel(
    const float* __restrict__ partial, float* __restrict__ out) {
    float e = 0.0f;
    #pragma unroll
    for (int i = 0; i < GRID / BLOCK; ++i)
        e += partial[i * BLOCK + threadIdx.x];
    float bs = block_reduce(e, threadIdx.x);
    if (threadIdx.x == 0) out[0] = bs;   // overwrites poison
}

// Fallback (ws too small): single-kernel atomic path, same swizzle.
__global__ __launch_bounds__(BLOCK) void energy_atomic_kernel(
    const float* __restrict__ mean, const float* __restrict__ variance,
    const float* __restrict__ noise, const float* __restrict__ target,
    float* __restrict__ out) {
    const int wg  = (blockIdx.x & 7) * (GRID / 8) + (blockIdx.x >> 3);
    const int idx = wg * BLOCK + threadIdx.x;
    float e = energy_elem(mean, variance, noise, target, idx);
    float bs = block_reduce(e, threadIdx.x);
    if (threadIdx.x == 0) atomicAdd(out, bs);
}

extern "C" void kernel_launch(void* const* d_in, const int* in_sizes, int n_in,
                              void* d_out, int out_size, void* d_ws, size_t ws_size,
                              hipStream_t stream) {
    const float* mean     = (const float*)d_in[0];
    const float* variance = (const float*)d_in[1];
    const float* noise    = (const float*)d_in[2];
    const float* target   = (const float*)d_in[3];
    float* out = (float*)d_out;

    if (ws_size >= (size_t)GRID * sizeof(float)) {
        float* partial = (float*)d_ws;
        energy_partial_kernel<<<GRID, BLOCK, 0, stream>>>(mean, variance, noise,
                                                          target, partial);
        reduce_partial_kernel<<<1, BLOCK, 0, stream>>>(partial, out);
    } else {
        hipMemsetAsync(out, 0, sizeof(float), stream);
        energy_atomic_kernel<<<GRID, BLOCK, 0, stream>>>(mean, variance, noise,
                                                         target, out);
    }
}